// Round 1
// baseline (389.758 us; speedup 1.0000x reference)
//
#include <hip/hip_runtime.h>

#define K_DIM 8192
#define N_DIM 8192
#define M_DIM 64

typedef __attribute__((ext_vector_type(8))) short bf16x8;   // 8 bf16 in 4 VGPRs
typedef __attribute__((ext_vector_type(4))) float fx4;

#define NTILE 64                    // output cols per block
#define KSPLIT 4                    // k-blocks per n-tile (across blocks)
#define KBLK (K_DIM / KSPLIT)       // 2048 k per block
#define KCHUNK (KBLK / 4)           // 512 k per wave

__device__ __forceinline__ short bf16_rne(float f) {
    unsigned u = __builtin_bit_cast(unsigned, f);
    u += 0x7FFFu + ((u >> 16) & 1u);
    return (short)(u >> 16);
}

// ---- x fp32 -> bf16 pre-convert (64*8192 elems, 8 per thread) ----
__global__ void hb_xconv(const float* __restrict__ x, short* __restrict__ xb) {
    const int i = blockIdx.x * blockDim.x + threadIdx.x;   // 65536 threads
    const fx4* xp = reinterpret_cast<const fx4*>(x) + (size_t)i * 2;
    fx4 a = xp[0], b = xp[1];
    bf16x8 o;
    #pragma unroll
    for (int j = 0; j < 4; ++j) { o[j] = bf16_rne(a[j]); o[j + 4] = bf16_rne(b[j]); }
    reinterpret_cast<bf16x8*>(xb)[i] = o;
}

// ---- main: binarize-on-the-fly MFMA GEMM + |w| sum ----
template<bool XBF16>
__global__ __launch_bounds__(256, 2)
void hb_gemm(const float* __restrict__ x, const float* __restrict__ w,
             const short* __restrict__ xb, float* __restrict__ out,
             float* __restrict__ absacc)
{
    __shared__ float red[4][M_DIM][NTILE];          // 64 KB
    const int tid  = threadIdx.x;
    const int wid  = tid >> 6;
    const int lane = tid & 63;
    const int lr   = lane & 15;                     // row within 16
    const int lg   = lane >> 4;                     // k-group 0..3

    const int nblk  = blockIdx.x & 127;             // 128 n-tiles
    const int kblk  = blockIdx.x >> 7;              // 4 k-blocks
    const int nbase = nblk * NTILE;
    const int kbase = kblk * KBLK + wid * KCHUNK;

    fx4 acc[4][4] = {};                             // 64x64 per wave
    float wabs = 0.f;

    #pragma unroll 2
    for (int ks = 0; ks < KCHUNK; ks += 32) {
        const int kpos = kbase + ks + lg * 8;

        // A fragments: x rows b = mt*16 + lr, 8 contiguous k
        bf16x8 afrag[4];
        #pragma unroll
        for (int mt = 0; mt < 4; ++mt) {
            const int b = mt * 16 + lr;
            if constexpr (XBF16) {
                afrag[mt] = *reinterpret_cast<const bf16x8*>(xb + (size_t)b * K_DIM + kpos);
            } else {
                const float* xp = x + (size_t)b * K_DIM + kpos;
                fx4 a0 = *reinterpret_cast<const fx4*>(xp);
                fx4 a1 = *reinterpret_cast<const fx4*>(xp + 4);
                bf16x8 f;
                #pragma unroll
                for (int j = 0; j < 4; ++j) { f[j] = bf16_rne(a0[j]); f[j + 4] = bf16_rne(a1[j]); }
                afrag[mt] = f;
            }
        }

        // B fragments: weight rows o = nbase + nt*16 + lr -> sign in bf16, fuse |w| sum
        bf16x8 bfrag[4];
        #pragma unroll
        for (int nt = 0; nt < 4; ++nt) {
            const float* wp = w + (size_t)(nbase + nt * 16 + lr) * K_DIM + kpos;
            fx4 w0 = *reinterpret_cast<const fx4*>(wp);
            fx4 w1 = *reinterpret_cast<const fx4*>(wp + 4);
            bf16x8 s;
            #pragma unroll
            for (int j = 0; j < 4; ++j) {
                const float v0 = w0[j], v1 = w1[j];
                wabs += fabsf(v0) + fabsf(v1);
                s[j]     = (v0 > 0.f) ? (short)0x3F80 : ((v0 < 0.f) ? (short)0xBF80 : (short)0);
                s[j + 4] = (v1 > 0.f) ? (short)0x3F80 : ((v1 < 0.f) ? (short)0xBF80 : (short)0);
            }
            bfrag[nt] = s;
        }

        #pragma unroll
        for (int mt = 0; mt < 4; ++mt)
            #pragma unroll
            for (int nt = 0; nt < 4; ++nt)
                acc[mt][nt] = __builtin_amdgcn_mfma_f32_16x16x32_bf16(
                    afrag[mt], bfrag[nt], acc[mt][nt], 0, 0, 0);
    }

    // |w| partial: wave shuffle-reduce, one atomic per wave
    #pragma unroll
    for (int off = 32; off > 0; off >>= 1)
        wabs += __shfl_down(wabs, off);
    if (lane == 0) atomicAdd(absacc, wabs);

    // block-reduce the 4 wave partials, then accumulate unscaled into d_out
    #pragma unroll
    for (int mt = 0; mt < 4; ++mt)
        #pragma unroll
        for (int nt = 0; nt < 4; ++nt)
            #pragma unroll
            for (int j = 0; j < 4; ++j)
                red[wid][mt * 16 + lg * 4 + j][nt * 16 + lr] = acc[mt][nt][j];
    __syncthreads();

    #pragma unroll
    for (int e = 0; e < 16; ++e) {
        const int p = e * 256 + tid;                // coalesced within row
        const int m = p >> 6;
        const int n = p & 63;
        const float s = red[0][m][n] + red[1][m][n] + red[2][m][n] + red[3][m][n];
        atomicAdd(out + (size_t)m * N_DIM + nbase + n, s);
    }
}

// ---- finalize: out *= mean(|w|) ----
__global__ void hb_scale(float* __restrict__ out, const float* __restrict__ absacc) {
    const float scale = absacc[0] * (1.0f / ((float)K_DIM * (float)N_DIM));
    const int i = blockIdx.x * blockDim.x + threadIdx.x;   // 131072 threads, one fx4 each
    fx4* p = reinterpret_cast<fx4*>(out);
    fx4 v = p[i];
    v *= scale;
    p[i] = v;
}

extern "C" void kernel_launch(void* const* d_in, const int* in_sizes, int n_in,
                              void* d_out, int out_size, void* d_ws, size_t ws_size,
                              hipStream_t stream) {
    const float* x = (const float*)d_in[0];
    const float* w = (const float*)d_in[1];
    float* out = (float*)d_out;

    float* absacc = (float*)d_ws;
    short* xb = (short*)((char*)d_ws + 256);
    const size_t xb_bytes = (size_t)M_DIM * K_DIM * sizeof(short);
    const bool use_xb = ws_size >= 256 + xb_bytes;

    hipMemsetAsync(d_out, 0, (size_t)out_size * sizeof(float), stream);
    hipMemsetAsync(d_ws, 0, 64, stream);

    if (use_xb) {
        hb_xconv<<<256, 256, 0, stream>>>(x, xb);
        hb_gemm<true><<<(N_DIM / NTILE) * KSPLIT, 256, 0, stream>>>(x, w, xb, out, absacc);
    } else {
        hb_gemm<false><<<(N_DIM / NTILE) * KSPLIT, 256, 0, stream>>>(x, w, nullptr, out, absacc);
    }
    hb_scale<<<512, 256, 0, stream>>>(out, absacc);
}